// Round 7
// baseline (205.228 us; speedup 1.0000x reference)
//
#include <hip/hip_runtime.h>
#include <hip/hip_bf16.h>
#include <math.h>

// Problem constants
#define BB   256   // batch
#define TT   256   // sequence
#define CIN  384   // n_embed
#define HS   64    // head size
#define BT   (BB*TT)

// softmax scale folded into q at projection time: 384^-0.5 * log2(e)
#define QSCL ((float)(0.051031036307982884 * 1.4426950408889634))

typedef __attribute__((ext_vector_type(8))) short short8;   // 8 bf16 = 4 VGPR
typedef __attribute__((ext_vector_type(4))) float floatx4;  // MFMA C/D

__device__ inline short bf16bits(float f) {
    union { __hip_bfloat16 h; short s; } u;
    u.h = __float2bfloat16(f);
    return u.s;
}

__device__ inline short8 cvt8(const float4& f0, const float4& f1) {
    union { __hip_bfloat162 h[4]; short8 s8; } u;
    u.h[0] = __float22bfloat162_rn(make_float2(f0.x, f0.y));
    u.h[1] = __float22bfloat162_rn(make_float2(f0.z, f0.w));
    u.h[2] = __float22bfloat162_rn(make_float2(f1.x, f1.y));
    u.h[3] = __float22bfloat162_rn(make_float2(f1.z, f1.w));
    return u.s8;
}

// ---------------------------------------------------------------------------
// Kernel 0: pack Wq|Wk|Wv -> Wt[n][k] bf16 (unchanged)
// ---------------------------------------------------------------------------
__global__ __launch_bounds__(256) void prep_wt(
    const float* __restrict__ Wq, const float* __restrict__ Wk,
    const float* __restrict__ Wv, short* __restrict__ Wt)
{
    const int idx = blockIdx.x * 256 + threadIdx.x;
    const int n  = idx / 384;
    const int kk = idx - n * 384;
    const float* W = (n < 64) ? Wq : (n < 128) ? Wk : Wv;
    Wt[idx] = bf16bits(W[kk * 64 + (n & 63)]);
}

// ---------------------------------------------------------------------------
// Kernel 1: QKV projection, LDS double-buffered bf16 MFMA GEMM.
// Grid 1024 (M-tile 64) x 256 thr (4 waves). Wave (wm,wn) = 32M x 96N
// = 2x6 16x16 tiles. x staged per block: 6 slabs [64 x 64] fp32->bf16 LDS
// (rows padded to 72 shorts), double-buffered.
// LDS union = 27648 B (2x4608-short stage / 3x4608-short epilogue)
// -> 5 blocks/CU by LDS; grid gives 4 independent blocks/CU = 16 waves/CU,
// barrier stalls overlap across 4 blocks (R6 lesson: independent blocks,
// not more waves per block).
// q pre-scaled by QSCL; V written transposed vT[b][h][t].
// ---------------------------------------------------------------------------
__global__ __launch_bounds__(256) void qkv_mfma(
    const float* __restrict__ x, const short* __restrict__ Wt,
    short* __restrict__ q, short* __restrict__ k, short* __restrict__ vT)
{
    __shared__ short smem[13824];   // 27648 B

    const int tid  = threadIdx.x;
    const int lane = tid & 63;
    const int w    = tid >> 6;        // 0..3
    const int wm   = w >> 1;          // 0..1 : M half (32 rows)
    const int wn   = w & 1;           // 0..1 : N half (96 cols)
    const int l15  = lane & 15;
    const int quad = lane >> 4;
    const int kq   = quad * 8;
    const int crow = quad * 4;

    const int mbase0 = blockIdx.x * 64;
    const int nbase  = wn * 96;

    floatx4 acc[2][6] = {};

    const short* wp[6];
#pragma unroll
    for (int nt = 0; nt < 6; ++nt)
        wp[nt] = Wt + (size_t)(nbase + nt * 16 + l15) * 384 + kq;

    // ---- prologue: stage slab 0 (512 short8 chunks over 256 threads) ----
#pragma unroll
    for (int i = 0; i < 2; ++i) {
        const int c   = i * 256 + tid;
        const int row = c >> 3;
        const int ch  = (c & 7) * 8;
        const float* p = x + (size_t)(mbase0 + row) * 384 + ch;
        *(short8*)&smem[row * 72 + ch] = cvt8(*(const float4*)p, *(const float4*)(p + 4));
    }
    __syncthreads();

#pragma unroll
    for (int s = 0; s < 6; ++s) {
        short* cur = smem + (s & 1) * 4608;
        short* nxt = smem + ((s & 1) ^ 1) * 4608;

        // B fragments for this slab (L2-hot)
        short8 bf[2][6];
#pragma unroll
        for (int nt = 0; nt < 6; ++nt) {
            bf[0][nt] = *(const short8*)(wp[nt] + s * 64);
            bf[1][nt] = *(const short8*)(wp[nt] + s * 64 + 32);
        }

        // issue global loads for slab s+1
        float4 pf[2][2];
        if (s < 5) {
#pragma unroll
            for (int i = 0; i < 2; ++i) {
                const int c   = i * 256 + tid;
                const int row = c >> 3;
                const int ch  = (c & 7) * 8;
                const float* p = x + (size_t)(mbase0 + row) * 384 + (s + 1) * 64 + ch;
                pf[i][0] = *(const float4*)p;
                pf[i][1] = *(const float4*)(p + 4);
            }
        }

        // compute slab s from LDS
#pragma unroll
        for (int ks = 0; ks < 2; ++ks) {
            short8 af[2];
#pragma unroll
            for (int mt = 0; mt < 2; ++mt)
                af[mt] = *(const short8*)&cur[(wm * 32 + mt * 16 + l15) * 72 + ks * 32 + kq];
#pragma unroll
            for (int mt = 0; mt < 2; ++mt)
#pragma unroll
                for (int nt = 0; nt < 6; ++nt)
                    acc[mt][nt] = __builtin_amdgcn_mfma_f32_16x16x32_bf16(
                        af[mt], bf[ks][nt], acc[mt][nt], 0, 0, 0);
        }

        // commit slab s+1
        if (s < 5) {
#pragma unroll
            for (int i = 0; i < 2; ++i) {
                const int c   = i * 256 + tid;
                const int row = c >> 3;
                const int ch  = (c & 7) * 8;
                *(short8*)&nxt[row * 72 + ch] = cvt8(pf[i][0], pf[i][1]);
            }
        }
        __syncthreads();
    }

    // ---- epilogue: route outputs through LDS for coalesced stores ----
    short (*q_lds)[72]  = (short(*)[72])  smem;            // 64x72
    short (*k_lds)[72]  = (short(*)[72]) (smem + 4608);    // 64x72
    short (*vt_lds)[72] = (short(*)[72]) (smem + 9216);    // 64x72 (h x t)

#pragma unroll
    for (int nt = 0; nt < 6; ++nt) {
        const int n = nbase + nt * 16 + l15;
#pragma unroll
        for (int mt = 0; mt < 2; ++mt) {
#pragma unroll
            for (int r = 0; r < 4; ++r) {
                const int m = wm * 32 + mt * 16 + crow + r;   // block-local row
                const float av = acc[mt][nt][r];
                if (n < 64)       q_lds[m][n]        = bf16bits(av * QSCL);
                else if (n < 128) k_lds[m][n - 64]   = bf16bits(av);
                else              vt_lds[n - 128][m] = bf16bits(av);
            }
        }
    }
    __syncthreads();

    const int b  = blockIdx.x >> 2;
    const int t0 = (blockIdx.x & 3) * 64;
#pragma unroll
    for (int i = 0; i < 2; ++i) {
        const int c   = i * 256 + tid;
        const int row = c >> 3;          // 0..63
        const int c8  = (c & 7) * 8;     // 0..56
        *(short8*)&q[(size_t)(mbase0 + row) * 64 + c8] = *(const short8*)&q_lds[row][c8];
        *(short8*)&k[(size_t)(mbase0 + row) * 64 + c8] = *(const short8*)&k_lds[row][c8];
        *(short8*)&vT[(size_t)(b * 64 + row) * 256 + t0 + c8] = *(const short8*)&vt_lds[row][c8];
    }
}

// ---------------------------------------------------------------------------
// Kernel 2: MFMA flash attention, single-pass unnormalized softmax
// (unchanged from R6).
// ---------------------------------------------------------------------------
__global__ __launch_bounds__(256) void attn_mfma(
    const short* __restrict__ q,
    const short* __restrict__ k,
    const short* __restrict__ vT,
    float* __restrict__ out)
{
    __shared__ short Ks[128][72];      // 18432 B
    __shared__ short Vt[64][136];      // 17408 B
    __shared__ short Ps[4][16][40];    //  5120 B

    const int tid  = threadIdx.x;
    const int b    = blockIdx.x >> 2;
    const int qt   = blockIdx.x & 3;
    const int lane = tid & 63;
    const int w    = tid >> 6;
    const int l15  = lane & 15;
    const int quad = lane >> 4;
    const int kq   = quad * 8;
    const int crow = quad * 4;

    const int q0g  = qt * 64 + w * 16;
    const int kmax = q0g + 16;

    short8 aq[2];
    {
        const short* qp = q + (size_t)(b * 256 + q0g + l15) * 64;
        aq[0] = *(const short8*)(qp + kq);
        aq[1] = *(const short8*)(qp + 32 + kq);
    }

    float lsum[4] = {0.f, 0.f, 0.f, 0.f};
    floatx4 O[4] = {};

    const int nstages = (qt >= 2) ? 2 : 1;
    for (int s = 0; s < nstages; ++s) {
        if (s) __syncthreads();
        const int sbase = s * 128;

#pragma unroll
        for (int i = 0; i < 4; ++i) {
            const int c   = i * 256 + tid;
            const int key = c >> 3;
            const int c8  = (c & 7) * 8;
            *(short8*)&Ks[key][c8] =
                *(const short8*)(k + (size_t)(b * 256 + sbase + key) * 64 + c8);
        }
#pragma unroll
        for (int i = 0; i < 4; ++i) {
            const int c  = i * 256 + tid;
            const int h  = c >> 4;
            const int t8 = (c & 15) * 8;
            *(short8*)&Vt[h][t8] =
                *(const short8*)(vT + (size_t)(b * 64 + h) * 256 + sbase + t8);
        }
        __syncthreads();

        const int rem = kmax - sbase;
        const int nch = rem >= 128 ? 4 : ((rem + 31) >> 5);
        for (int c = 0; c < nch; ++c) {
            const int cb = c * 32;

            floatx4 st[2];
#pragma unroll
            for (int t = 0; t < 2; ++t) {
                const short8 b0 = *(const short8*)&Ks[cb + t * 16 + l15][kq];
                const short8 b1 = *(const short8*)&Ks[cb + t * 16 + l15][32 + kq];
                floatx4 z = {};
                z = __builtin_amdgcn_mfma_f32_16x16x32_bf16(aq[0], b0, z, 0, 0, 0);
                z = __builtin_amdgcn_mfma_f32_16x16x32_bf16(aq[1], b1, z, 0, 0, 0);
                st[t] = z;
            }

#pragma unroll
            for (int t = 0; t < 2; ++t)
#pragma unroll
                for (int r = 0; r < 4; ++r) {
                    const int key  = sbase + cb + t * 16 + l15;
                    const int qrow = q0g + crow + r;
                    float p = __builtin_amdgcn_exp2f(st[t][r]);
                    p = (key <= qrow) ? p : 0.f;
                    lsum[r] += p;
                    Ps[w][crow + r][t * 16 + l15] = bf16bits(p);
                }

            asm volatile("s_waitcnt lgkmcnt(0)" ::: "memory");

            const short8 pa = *(const short8*)&Ps[w][l15][kq];
#pragma unroll
            for (int n = 0; n < 4; ++n) {
                const short8 bv = *(const short8*)&Vt[n * 16 + l15][cb + kq];
                O[n] = __builtin_amdgcn_mfma_f32_16x16x32_bf16(pa, bv, O[n], 0, 0, 0);
            }
        }
    }

#pragma unroll
    for (int off = 1; off < 16; off <<= 1)
#pragma unroll
        for (int r = 0; r < 4; ++r)
            lsum[r] += __shfl_xor(lsum[r], off, 16);

    float inv[4];
#pragma unroll
    for (int r = 0; r < 4; ++r) inv[r] = 1.f / lsum[r];
#pragma unroll
    for (int n = 0; n < 4; ++n)
#pragma unroll
        for (int r = 0; r < 4; ++r)
            out[(size_t)(b * 256 + q0g + crow + r) * 64 + n * 16 + l15] = O[n][r] * inv[r];
}

// ---------------------------------------------------------------------------
// Launch
// ---------------------------------------------------------------------------
extern "C" void kernel_launch(void* const* d_in, const int* in_sizes, int n_in,
                              void* d_out, int out_size, void* d_ws, size_t ws_size,
                              hipStream_t stream)
{
    const float* x  = (const float*)d_in[0];
    const float* Wq = (const float*)d_in[1];
    const float* Wk = (const float*)d_in[2];
    const float* Wv = (const float*)d_in[3];
    float* out = (float*)d_out;

    short* Wt = (short*)d_ws;
    short* qb = (short*)((char*)d_ws + 256 * 1024);
    short* kb = qb + (size_t)BT * HS;
    short* vT = kb + (size_t)BT * HS;

    prep_wt<<<(192 * 384) / 256, 256, 0, stream>>>(Wq, Wk, Wv, Wt);
    qkv_mfma<<<BT / 64, 256, 0, stream>>>(x, Wt, qb, kb, vT);
    attn_mfma<<<BB * 4, 256, 0, stream>>>(qb, kb, vT, out);
}

// Round 8
// 189.439 us; speedup vs baseline: 1.0833x; 1.0833x over previous
//
#include <hip/hip_runtime.h>
#include <hip/hip_bf16.h>
#include <math.h>

// Problem constants
#define BB   256   // batch
#define TT   256   // sequence
#define CIN  384   // n_embed
#define HS   64    // head size
#define BT   (BB*TT)

// softmax scale folded into q at projection time: 384^-0.5 * log2(e)
#define QSCL ((float)(0.051031036307982884 * 1.4426950408889634))

typedef __attribute__((ext_vector_type(8))) short short8;   // 8 bf16 = 4 VGPR
typedef __attribute__((ext_vector_type(4))) float floatx4;  // MFMA C/D

__device__ inline short bf16bits(float f) {
    union { __hip_bfloat16 h; short s; } u;
    u.h = __float2bfloat16(f);
    return u.s;
}

__device__ inline short8 cvt8(const float4& f0, const float4& f1) {
    union { __hip_bfloat162 h[4]; short8 s8; } u;
    u.h[0] = __float22bfloat162_rn(make_float2(f0.x, f0.y));
    u.h[1] = __float22bfloat162_rn(make_float2(f0.z, f0.w));
    u.h[2] = __float22bfloat162_rn(make_float2(f1.x, f1.y));
    u.h[3] = __float22bfloat162_rn(make_float2(f1.z, f1.w));
    return u.s8;
}

// ---------------------------------------------------------------------------
// Kernel 0: pack Wq|Wk|Wv -> Wt[n][k] bf16 (unchanged)
// ---------------------------------------------------------------------------
__global__ __launch_bounds__(256) void prep_wt(
    const float* __restrict__ Wq, const float* __restrict__ Wk,
    const float* __restrict__ Wv, short* __restrict__ Wt)
{
    const int idx = blockIdx.x * 256 + threadIdx.x;
    const int n  = idx / 384;
    const int kk = idx - n * 384;
    const float* W = (n < 64) ? Wq : (n < 128) ? Wk : Wv;
    Wt[idx] = bf16bits(W[kk * 64 + (n & 63)]);
}

// ---------------------------------------------------------------------------
// Kernel 1: QKV projection — R5's best-measured config restored verbatim.
// Grid 512 = 128 M-rows/block, 4 waves: (wm,wn) -> 64M x 96N = 4x6 tiles
// (48 MFMA per wave per barrier interval — the variable that tracks perf:
// R5 <59us vs R6/R7 ~75us at 24 MFMA/interval).
// x staged per block: 6 slabs [128 x 64] fp32 -> bf16 LDS (rows padded to
// 72 shorts), double-buffered. Wt (L2-hot) direct-to-register per slab.
// Delta vs R5: q pre-scaled by QSCL for the unnormalized-softmax attn.
// ---------------------------------------------------------------------------
__global__ __launch_bounds__(256) void qkv_mfma(
    const float* __restrict__ x, const short* __restrict__ Wt,
    short* __restrict__ q, short* __restrict__ k, short* __restrict__ vT)
{
    __shared__ short smem[27136];   // 54272 B: 2x stage[128][72] / epilogue union

    const int tid  = threadIdx.x;
    const int lane = tid & 63;
    const int w    = tid >> 6;
    const int wm   = w >> 1;
    const int wn   = w & 1;
    const int l15  = lane & 15;
    const int quad = lane >> 4;
    const int kq   = quad * 8;
    const int crow = quad * 4;

    const int mbase0 = blockIdx.x * 128;
    const int nbase  = wn * 96;

    floatx4 acc[4][6] = {};

    const short* wp[6];
#pragma unroll
    for (int nt = 0; nt < 6; ++nt)
        wp[nt] = Wt + (size_t)(nbase + nt * 16 + l15) * 384 + kq;

    // ---- prologue: stage slab 0 ----
#pragma unroll
    for (int i = 0; i < 4; ++i) {
        const int c   = i * 256 + tid;
        const int row = c >> 3;
        const int ch  = (c & 7) * 8;
        const float* p = x + (size_t)(mbase0 + row) * 384 + ch;
        *(short8*)&smem[row * 72 + ch] = cvt8(*(const float4*)p, *(const float4*)(p + 4));
    }
    __syncthreads();

#pragma unroll
    for (int s = 0; s < 6; ++s) {
        short* cur = smem + (s & 1) * 9216;
        short* nxt = smem + ((s & 1) ^ 1) * 9216;

        // B fragments for this slab (L2-hot)
        short8 bf[2][6];
#pragma unroll
        for (int nt = 0; nt < 6; ++nt) {
            bf[0][nt] = *(const short8*)(wp[nt] + s * 64);
            bf[1][nt] = *(const short8*)(wp[nt] + s * 64 + 32);
        }

        // issue global loads for slab s+1 (consumed after MFMAs)
        float4 pf[4][2];
        if (s < 5) {
#pragma unroll
            for (int i = 0; i < 4; ++i) {
                const int c   = i * 256 + tid;
                const int row = c >> 3;
                const int ch  = (c & 7) * 8;
                const float* p = x + (size_t)(mbase0 + row) * 384 + (s + 1) * 64 + ch;
                pf[i][0] = *(const float4*)p;
                pf[i][1] = *(const float4*)(p + 4);
            }
        }

        // compute slab s from LDS
#pragma unroll
        for (int ks = 0; ks < 2; ++ks) {
            short8 af[4];
#pragma unroll
            for (int mt = 0; mt < 4; ++mt)
                af[mt] = *(const short8*)&cur[(wm * 64 + mt * 16 + l15) * 72 + ks * 32 + kq];
#pragma unroll
            for (int mt = 0; mt < 4; ++mt)
#pragma unroll
                for (int nt = 0; nt < 6; ++nt)
                    acc[mt][nt] = __builtin_amdgcn_mfma_f32_16x16x32_bf16(
                        af[mt], bf[ks][nt], acc[mt][nt], 0, 0, 0);
        }

        // commit slab s+1 to the other buffer
        if (s < 5) {
#pragma unroll
            for (int i = 0; i < 4; ++i) {
                const int c   = i * 256 + tid;
                const int row = c >> 3;
                const int ch  = (c & 7) * 8;
                *(short8*)&nxt[row * 72 + ch] = cvt8(pf[i][0], pf[i][1]);
            }
        }
        __syncthreads();
    }

    // ---- epilogue: route outputs through LDS for coalesced stores ----
    short (*q_lds)[72]   = (short(*)[72])  smem;            // 128x72
    short (*k_lds)[72]   = (short(*)[72]) (smem + 9216);    // 128x72
    short (*vt_lds)[136] = (short(*)[136])(smem + 18432);   // 64x136

#pragma unroll
    for (int nt = 0; nt < 6; ++nt) {
        const int n = nbase + nt * 16 + l15;
#pragma unroll
        for (int mt = 0; mt < 4; ++mt) {
#pragma unroll
            for (int r = 0; r < 4; ++r) {
                const int m = wm * 64 + mt * 16 + crow + r;   // block-local row
                const float av = acc[mt][nt][r];
                if (n < 64)       q_lds[m][n]        = bf16bits(av * QSCL);
                else if (n < 128) k_lds[m][n - 64]   = bf16bits(av);
                else              vt_lds[n - 128][m] = bf16bits(av);
            }
        }
    }
    __syncthreads();

    const int b  = blockIdx.x >> 1;
    const int t0 = (blockIdx.x & 1) * 128;
#pragma unroll
    for (int i = 0; i < 4; ++i) {
        const int c = i * 256 + tid;
        {   // q, k: 128 rows x 64 cols
            const int row = c >> 3;
            const int c8  = (c & 7) * 8;
            *(short8*)&q[(size_t)(mbase0 + row) * 64 + c8] = *(const short8*)&q_lds[row][c8];
            *(short8*)&k[(size_t)(mbase0 + row) * 64 + c8] = *(const short8*)&k_lds[row][c8];
        }
        {   // vT: 64 h-rows x 128 t-cols
            const int h  = c >> 4;
            const int t8 = (c & 15) * 8;
            *(short8*)&vT[(size_t)(b * 64 + h) * 256 + t0 + t8] = *(const short8*)&vt_lds[h][t8];
        }
    }
}

// ---------------------------------------------------------------------------
// Kernel 2: MFMA flash attention, single-pass unnormalized softmax
// (unchanged — best measured, R6).
// ---------------------------------------------------------------------------
__global__ __launch_bounds__(256) void attn_mfma(
    const short* __restrict__ q,
    const short* __restrict__ k,
    const short* __restrict__ vT,
    float* __restrict__ out)
{
    __shared__ short Ks[128][72];      // 18432 B
    __shared__ short Vt[64][136];      // 17408 B
    __shared__ short Ps[4][16][40];    //  5120 B

    const int tid  = threadIdx.x;
    const int b    = blockIdx.x >> 2;
    const int qt   = blockIdx.x & 3;
    const int lane = tid & 63;
    const int w    = tid >> 6;
    const int l15  = lane & 15;
    const int quad = lane >> 4;
    const int kq   = quad * 8;
    const int crow = quad * 4;

    const int q0g  = qt * 64 + w * 16;
    const int kmax = q0g + 16;

    short8 aq[2];
    {
        const short* qp = q + (size_t)(b * 256 + q0g + l15) * 64;
        aq[0] = *(const short8*)(qp + kq);
        aq[1] = *(const short8*)(qp + 32 + kq);
    }

    float lsum[4] = {0.f, 0.f, 0.f, 0.f};
    floatx4 O[4] = {};

    const int nstages = (qt >= 2) ? 2 : 1;
    for (int s = 0; s < nstages; ++s) {
        if (s) __syncthreads();
        const int sbase = s * 128;

#pragma unroll
        for (int i = 0; i < 4; ++i) {
            const int c   = i * 256 + tid;
            const int key = c >> 3;
            const int c8  = (c & 7) * 8;
            *(short8*)&Ks[key][c8] =
                *(const short8*)(k + (size_t)(b * 256 + sbase + key) * 64 + c8);
        }
#pragma unroll
        for (int i = 0; i < 4; ++i) {
            const int c  = i * 256 + tid;
            const int h  = c >> 4;
            const int t8 = (c & 15) * 8;
            *(short8*)&Vt[h][t8] =
                *(const short8*)(vT + (size_t)(b * 64 + h) * 256 + sbase + t8);
        }
        __syncthreads();

        const int rem = kmax - sbase;
        const int nch = rem >= 128 ? 4 : ((rem + 31) >> 5);
        for (int c = 0; c < nch; ++c) {
            const int cb = c * 32;

            floatx4 st[2];
#pragma unroll
            for (int t = 0; t < 2; ++t) {
                const short8 b0 = *(const short8*)&Ks[cb + t * 16 + l15][kq];
                const short8 b1 = *(const short8*)&Ks[cb + t * 16 + l15][32 + kq];
                floatx4 z = {};
                z = __builtin_amdgcn_mfma_f32_16x16x32_bf16(aq[0], b0, z, 0, 0, 0);
                z = __builtin_amdgcn_mfma_f32_16x16x32_bf16(aq[1], b1, z, 0, 0, 0);
                st[t] = z;
            }

#pragma unroll
            for (int t = 0; t < 2; ++t)
#pragma unroll
                for (int r = 0; r < 4; ++r) {
                    const int key  = sbase + cb + t * 16 + l15;
                    const int qrow = q0g + crow + r;
                    float p = __builtin_amdgcn_exp2f(st[t][r]);
                    p = (key <= qrow) ? p : 0.f;
                    lsum[r] += p;
                    Ps[w][crow + r][t * 16 + l15] = bf16bits(p);
                }

            asm volatile("s_waitcnt lgkmcnt(0)" ::: "memory");

            const short8 pa = *(const short8*)&Ps[w][l15][kq];
#pragma unroll
            for (int n = 0; n < 4; ++n) {
                const short8 bv = *(const short8*)&Vt[n * 16 + l15][cb + kq];
                O[n] = __builtin_amdgcn_mfma_f32_16x16x32_bf16(pa, bv, O[n], 0, 0, 0);
            }
        }
    }

#pragma unroll
    for (int off = 1; off < 16; off <<= 1)
#pragma unroll
        for (int r = 0; r < 4; ++r)
            lsum[r] += __shfl_xor(lsum[r], off, 16);

    float inv[4];
#pragma unroll
    for (int r = 0; r < 4; ++r) inv[r] = 1.f / lsum[r];
#pragma unroll
    for (int n = 0; n < 4; ++n)
#pragma unroll
        for (int r = 0; r < 4; ++r)
            out[(size_t)(b * 256 + q0g + crow + r) * 64 + n * 16 + l15] = O[n][r] * inv[r];
}

// ---------------------------------------------------------------------------
// Launch
// ---------------------------------------------------------------------------
extern "C" void kernel_launch(void* const* d_in, const int* in_sizes, int n_in,
                              void* d_out, int out_size, void* d_ws, size_t ws_size,
                              hipStream_t stream)
{
    const float* x  = (const float*)d_in[0];
    const float* Wq = (const float*)d_in[1];
    const float* Wk = (const float*)d_in[2];
    const float* Wv = (const float*)d_in[3];
    float* out = (float*)d_out;

    short* Wt = (short*)d_ws;
    short* qb = (short*)((char*)d_ws + 256 * 1024);
    short* kb = qb + (size_t)BT * HS;
    short* vT = kb + (size_t)BT * HS;

    prep_wt<<<(192 * 384) / 256, 256, 0, stream>>>(Wq, Wk, Wv, Wt);
    qkv_mfma<<<BT / 128, 256, 0, stream>>>(x, Wt, qb, kb, vT);
    attn_mfma<<<BB * 4, 256, 0, stream>>>(qb, kb, vT, out);
}

// Round 9
// 181.758 us; speedup vs baseline: 1.1291x; 1.0423x over previous
//
#include <hip/hip_runtime.h>
#include <hip/hip_bf16.h>
#include <math.h>

// Problem constants
#define BB   256   // batch
#define TT   256   // sequence
#define CIN  384   // n_embed
#define HS   64    // head size
#define BT   (BB*TT)

// softmax scale folded into q at projection time: 384^-0.5 * log2(e)
#define QSCL ((float)(0.051031036307982884 * 1.4426950408889634))

typedef __attribute__((ext_vector_type(8))) short short8;   // 8 bf16 = 4 VGPR
typedef __attribute__((ext_vector_type(4))) float floatx4;  // MFMA C/D

__device__ inline short bf16bits(float f) {
    union { __hip_bfloat16 h; short s; } u;
    u.h = __float2bfloat16(f);
    return u.s;
}

__device__ inline short8 cvt8(const float4& f0, const float4& f1) {
    union { __hip_bfloat162 h[4]; short8 s8; } u;
    u.h[0] = __float22bfloat162_rn(make_float2(f0.x, f0.y));
    u.h[1] = __float22bfloat162_rn(make_float2(f0.z, f0.w));
    u.h[2] = __float22bfloat162_rn(make_float2(f1.x, f1.y));
    u.h[3] = __float22bfloat162_rn(make_float2(f1.z, f1.w));
    return u.s8;
}

// ---------------------------------------------------------------------------
// Kernel 0: pack Wq|Wk|Wv -> Wt[n][k] bf16 (unchanged)
// ---------------------------------------------------------------------------
__global__ __launch_bounds__(256) void prep_wt(
    const float* __restrict__ Wq, const float* __restrict__ Wk,
    const float* __restrict__ Wv, short* __restrict__ Wt)
{
    const int idx = blockIdx.x * 256 + threadIdx.x;
    const int n  = idx / 384;
    const int kk = idx - n * 384;
    const float* W = (n < 64) ? Wq : (n < 128) ? Wk : Wv;
    Wt[idx] = bf16bits(W[kk * 64 + (n & 63)]);
}

// ---------------------------------------------------------------------------
// FUSED kernel: one block per batch element. 512 threads = 8 waves.
// Phase 1: QKV GEMM (M=256 tokens, N=192, K=384), R5's per-wave shape
//   (wm=w>>1 in 0..3 -> 64M; wn=w&1 -> 96N; 4x6 tiles, 48 MFMA/interval),
//   x staged in 6 double-buffered [256x64] fp32->bf16 LDS slabs (72-padded).
//   Outputs written ONLY to LDS: q (QSCL-prescaled), k, V transposed.
// Phase 2: causal attention entirely from LDS (no staging, no global
//   intermediates). Wave w owns rows w*32..w*32+31 as two 16-row groups;
//   unnormalized exp2 softmax (scale folded into q), P through wave-private
//   LDS (m120 pattern), O accum in registers, fp32 out stores.
// LDS layout (shorts), total 117760 B (<= 160 KiB GROUP segment):
//   [0      ) stageA / q_lds [256][72]
//   [18432  ) stageB / k_lds [256][72]
//   [36864  ) vt    [64][264]
//   [53760  ) Ps    [8][16][40]
// ---------------------------------------------------------------------------
__global__ __launch_bounds__(512) void fused_head(
    const float* __restrict__ x, const short* __restrict__ Wt,
    float* __restrict__ out)
{
    __shared__ short smem[58880];   // 117760 B

    const int tid  = threadIdx.x;
    const int b    = blockIdx.x;
    const int lane = tid & 63;
    const int w    = tid >> 6;        // 0..7
    const int wm   = w >> 1;          // 0..3 : 64-row M strip
    const int wn   = w & 1;           // 0..1 : 96-col N half
    const int l15  = lane & 15;
    const int quad = lane >> 4;
    const int kq   = quad * 8;
    const int crow = quad * 4;

    const int nbase = wn * 96;
    const float* xb = x + (size_t)b * 256 * 384;

    floatx4 acc[4][6] = {};

    const short* wp[6];
#pragma unroll
    for (int nt = 0; nt < 6; ++nt)
        wp[nt] = Wt + (size_t)(nbase + nt * 16 + l15) * 384 + kq;

    // ---- phase 1 prologue: stage slab 0 (2048 chunks of 32B over 512 thr) --
#pragma unroll
    for (int i = 0; i < 4; ++i) {
        const int c   = i * 512 + tid;
        const int row = c >> 3;
        const int ch  = (c & 7) * 8;
        const float* p = xb + (size_t)row * 384 + ch;
        *(short8*)&smem[row * 72 + ch] = cvt8(*(const float4*)p, *(const float4*)(p + 4));
    }
    __syncthreads();

#pragma unroll
    for (int s = 0; s < 6; ++s) {
        short* cur = smem + (s & 1) * 18432;
        short* nxt = smem + ((s & 1) ^ 1) * 18432;

        // B fragments (L2-hot Wt)
        short8 bf[2][6];
#pragma unroll
        for (int nt = 0; nt < 6; ++nt) {
            bf[0][nt] = *(const short8*)(wp[nt] + s * 64);
            bf[1][nt] = *(const short8*)(wp[nt] + s * 64 + 32);
        }

        // issue global loads for slab s+1
        float4 pf[4][2];
        if (s < 5) {
#pragma unroll
            for (int i = 0; i < 4; ++i) {
                const int c   = i * 512 + tid;
                const int row = c >> 3;
                const int ch  = (c & 7) * 8;
                const float* p = xb + (size_t)row * 384 + (s + 1) * 64 + ch;
                pf[i][0] = *(const float4*)p;
                pf[i][1] = *(const float4*)(p + 4);
            }
        }

        // compute slab s from LDS
#pragma unroll
        for (int ks = 0; ks < 2; ++ks) {
            short8 af[4];
#pragma unroll
            for (int mt = 0; mt < 4; ++mt)
                af[mt] = *(const short8*)&cur[(wm * 64 + mt * 16 + l15) * 72 + ks * 32 + kq];
#pragma unroll
            for (int mt = 0; mt < 4; ++mt)
#pragma unroll
                for (int nt = 0; nt < 6; ++nt)
                    acc[mt][nt] = __builtin_amdgcn_mfma_f32_16x16x32_bf16(
                        af[mt], bf[ks][nt], acc[mt][nt], 0, 0, 0);
        }

        // commit slab s+1
        if (s < 5) {
#pragma unroll
            for (int i = 0; i < 4; ++i) {
                const int c   = i * 512 + tid;
                const int row = c >> 3;
                const int ch  = (c & 7) * 8;
                *(short8*)&nxt[row * 72 + ch] = cvt8(pf[i][0], pf[i][1]);
            }
        }
        __syncthreads();
    }

    // ---- phase 1 epilogue: q/k/vT into LDS (stage buffers are dead) ----
    short* q_lds = smem;             // [256][72]
    short* k_lds = smem + 18432;     // [256][72]
    short* vt    = smem + 36864;     // [64][264]
    short* Ps    = smem + 53760;     // [8][16][40]

#pragma unroll
    for (int nt = 0; nt < 6; ++nt) {
        const int n = nbase + nt * 16 + l15;
#pragma unroll
        for (int mt = 0; mt < 4; ++mt) {
#pragma unroll
            for (int r = 0; r < 4; ++r) {
                const int m = wm * 64 + mt * 16 + crow + r;   // token row 0..255
                const float av = acc[mt][nt][r];
                if (n < 64)       q_lds[m * 72 + n]          = bf16bits(av * QSCL);
                else if (n < 128) k_lds[m * 72 + (n - 64)]   = bf16bits(av);
                else              vt[(n - 128) * 264 + m]    = bf16bits(av);
            }
        }
    }
    __syncthreads();

    // ---- phase 2: attention from LDS. wave w owns rows w*32 .. w*32+31 ----
#pragma unroll
    for (int g = 0; g < 2; ++g) {
        const int r0 = w * 32 + g * 16;

        short8 aq0, aq1;
        aq0 = *(const short8*)&q_lds[(r0 + l15) * 72 + kq];
        aq1 = *(const short8*)&q_lds[(r0 + l15) * 72 + 32 + kq];

        float lsum[4] = {0.f, 0.f, 0.f, 0.f};
        floatx4 O[4] = {};

        const int nch = (r0 + 47) >> 5;   // chunks of 32 keys, causal bound
        for (int c = 0; c < nch; ++c) {
            const int cb = c * 32;

            floatx4 st[2];
#pragma unroll
            for (int t = 0; t < 2; ++t) {
                const short8 b0 = *(const short8*)&k_lds[(cb + t * 16 + l15) * 72 + kq];
                const short8 b1 = *(const short8*)&k_lds[(cb + t * 16 + l15) * 72 + 32 + kq];
                floatx4 z = {};
                z = __builtin_amdgcn_mfma_f32_16x16x32_bf16(aq0, b0, z, 0, 0, 0);
                z = __builtin_amdgcn_mfma_f32_16x16x32_bf16(aq1, b1, z, 0, 0, 0);
                st[t] = z;
            }

#pragma unroll
            for (int t = 0; t < 2; ++t)
#pragma unroll
                for (int r = 0; r < 4; ++r) {
                    const int key  = cb + t * 16 + l15;
                    const int qrow = r0 + crow + r;
                    float p = __builtin_amdgcn_exp2f(st[t][r]);
                    p = (key <= qrow) ? p : 0.f;
                    lsum[r] += p;
                    Ps[w * 640 + (crow + r) * 40 + t * 16 + l15] = bf16bits(p);
                }

            // wave-private LDS write->read ordering
            asm volatile("s_waitcnt lgkmcnt(0)" ::: "memory");

            const short8 pa = *(const short8*)&Ps[w * 640 + l15 * 40 + kq];
#pragma unroll
            for (int n = 0; n < 4; ++n) {
                const short8 bv = *(const short8*)&vt[(n * 16 + l15) * 264 + cb + kq];
                O[n] = __builtin_amdgcn_mfma_f32_16x16x32_bf16(pa, bv, O[n], 0, 0, 0);
            }
        }

#pragma unroll
        for (int off = 1; off < 16; off <<= 1)
#pragma unroll
            for (int r = 0; r < 4; ++r)
                lsum[r] += __shfl_xor(lsum[r], off, 16);

        float inv[4];
#pragma unroll
        for (int r = 0; r < 4; ++r) inv[r] = 1.f / lsum[r];
#pragma unroll
        for (int n = 0; n < 4; ++n)
#pragma unroll
            for (int r = 0; r < 4; ++r)
                out[(size_t)(b * 256 + r0 + crow + r) * 64 + n * 16 + l15] = O[n][r] * inv[r];
    }
}

// ===========================================================================
// Fallback path (proven R8 kernels) — used only if the fused launch errors.
// ===========================================================================
__global__ __launch_bounds__(256) void qkv_mfma(
    const float* __restrict__ x, const short* __restrict__ Wt,
    short* __restrict__ q, short* __restrict__ k, short* __restrict__ vT)
{
    __shared__ short smem[27136];

    const int tid  = threadIdx.x;
    const int lane = tid & 63;
    const int w    = tid >> 6;
    const int wm   = w >> 1;
    const int wn   = w & 1;
    const int l15  = lane & 15;
    const int quad = lane >> 4;
    const int kq   = quad * 8;
    const int crow = quad * 4;

    const int mbase0 = blockIdx.x * 128;
    const int nbase  = wn * 96;

    floatx4 acc[4][6] = {};

    const short* wp[6];
#pragma unroll
    for (int nt = 0; nt < 6; ++nt)
        wp[nt] = Wt + (size_t)(nbase + nt * 16 + l15) * 384 + kq;

#pragma unroll
    for (int i = 0; i < 4; ++i) {
        const int c   = i * 256 + tid;
        const int row = c >> 3;
        const int ch  = (c & 7) * 8;
        const float* p = x + (size_t)(mbase0 + row) * 384 + ch;
        *(short8*)&smem[row * 72 + ch] = cvt8(*(const float4*)p, *(const float4*)(p + 4));
    }
    __syncthreads();

#pragma unroll
    for (int s = 0; s < 6; ++s) {
        short* cur = smem + (s & 1) * 9216;
        short* nxt = smem + ((s & 1) ^ 1) * 9216;

        short8 bf[2][6];
#pragma unroll
        for (int nt = 0; nt < 6; ++nt) {
            bf[0][nt] = *(const short8*)(wp[nt] + s * 64);
            bf[1][nt] = *(const short8*)(wp[nt] + s * 64 + 32);
        }

        float4 pf[4][2];
        if (s < 5) {
#pragma unroll
            for (int i = 0; i < 4; ++i) {
                const int c   = i * 256 + tid;
                const int row = c >> 3;
                const int ch  = (c & 7) * 8;
                const float* p = x + (size_t)(mbase0 + row) * 384 + (s + 1) * 64 + ch;
                pf[i][0] = *(const float4*)p;
                pf[i][1] = *(const float4*)(p + 4);
            }
        }

#pragma unroll
        for (int ks = 0; ks < 2; ++ks) {
            short8 af[4];
#pragma unroll
            for (int mt = 0; mt < 4; ++mt)
                af[mt] = *(const short8*)&cur[(wm * 64 + mt * 16 + l15) * 72 + ks * 32 + kq];
#pragma unroll
            for (int mt = 0; mt < 4; ++mt)
#pragma unroll
                for (int nt = 0; nt < 6; ++nt)
                    acc[mt][nt] = __builtin_amdgcn_mfma_f32_16x16x32_bf16(
                        af[mt], bf[ks][nt], acc[mt][nt], 0, 0, 0);
        }

        if (s < 5) {
#pragma unroll
            for (int i = 0; i < 4; ++i) {
                const int c   = i * 256 + tid;
                const int row = c >> 3;
                const int ch  = (c & 7) * 8;
                *(short8*)&nxt[row * 72 + ch] = cvt8(pf[i][0], pf[i][1]);
            }
        }
        __syncthreads();
    }

    short (*q_lds)[72]   = (short(*)[72])  smem;
    short (*k_lds)[72]   = (short(*)[72]) (smem + 9216);
    short (*vt_lds)[136] = (short(*)[136])(smem + 18432);

#pragma unroll
    for (int nt = 0; nt < 6; ++nt) {
        const int n = nbase + nt * 16 + l15;
#pragma unroll
        for (int mt = 0; mt < 4; ++mt) {
#pragma unroll
            for (int r = 0; r < 4; ++r) {
                const int m = wm * 64 + mt * 16 + crow + r;
                const float av = acc[mt][nt][r];
                if (n < 64)       q_lds[m][n]        = bf16bits(av * QSCL);
                else if (n < 128) k_lds[m][n - 64]   = bf16bits(av);
                else              vt_lds[n - 128][m] = bf16bits(av);
            }
        }
    }
    __syncthreads();

    const int bb = blockIdx.x >> 1;
    const int t0 = (blockIdx.x & 1) * 128;
#pragma unroll
    for (int i = 0; i < 4; ++i) {
        const int c = i * 256 + tid;
        {
            const int row = c >> 3;
            const int c8  = (c & 7) * 8;
            *(short8*)&q[(size_t)(mbase0 + row) * 64 + c8] = *(const short8*)&q_lds[row][c8];
            *(short8*)&k[(size_t)(mbase0 + row) * 64 + c8] = *(const short8*)&k_lds[row][c8];
        }
        {
            const int h  = c >> 4;
            const int t8 = (c & 15) * 8;
            *(short8*)&vT[(size_t)(bb * 64 + h) * 256 + t0 + t8] = *(const short8*)&vt_lds[h][t8];
        }
    }
}

__global__ __launch_bounds__(256) void attn_mfma(
    const short* __restrict__ q,
    const short* __restrict__ k,
    const short* __restrict__ vT,
    float* __restrict__ out)
{
    __shared__ short Ks[128][72];
    __shared__ short Vt[64][136];
    __shared__ short Ps[4][16][40];

    const int tid  = threadIdx.x;
    const int b    = blockIdx.x >> 2;
    const int qt   = blockIdx.x & 3;
    const int lane = tid & 63;
    const int w    = tid >> 6;
    const int l15  = lane & 15;
    const int quad = lane >> 4;
    const int kq   = quad * 8;
    const int crow = quad * 4;

    const int q0g  = qt * 64 + w * 16;
    const int kmax = q0g + 16;

    short8 aq[2];
    {
        const short* qp = q + (size_t)(b * 256 + q0g + l15) * 64;
        aq[0] = *(const short8*)(qp + kq);
        aq[1] = *(const short8*)(qp + 32 + kq);
    }

    float lsum[4] = {0.f, 0.f, 0.f, 0.f};
    floatx4 O[4] = {};

    const int nstages = (qt >= 2) ? 2 : 1;
    for (int s = 0; s < nstages; ++s) {
        if (s) __syncthreads();
        const int sbase = s * 128;

#pragma unroll
        for (int i = 0; i < 4; ++i) {
            const int c   = i * 256 + tid;
            const int key = c >> 3;
            const int c8  = (c & 7) * 8;
            *(short8*)&Ks[key][c8] =
                *(const short8*)(k + (size_t)(b * 256 + sbase + key) * 64 + c8);
        }
#pragma unroll
        for (int i = 0; i < 4; ++i) {
            const int c  = i * 256 + tid;
            const int h  = c >> 4;
            const int t8 = (c & 15) * 8;
            *(short8*)&Vt[h][t8] =
                *(const short8*)(vT + (size_t)(b * 64 + h) * 256 + sbase + t8);
        }
        __syncthreads();

        const int rem = kmax - sbase;
        const int nch = rem >= 128 ? 4 : ((rem + 31) >> 5);
        for (int c = 0; c < nch; ++c) {
            const int cb = c * 32;

            floatx4 st[2];
#pragma unroll
            for (int t = 0; t < 2; ++t) {
                const short8 b0 = *(const short8*)&Ks[cb + t * 16 + l15][kq];
                const short8 b1 = *(const short8*)&Ks[cb + t * 16 + l15][32 + kq];
                floatx4 z = {};
                z = __builtin_amdgcn_mfma_f32_16x16x32_bf16(aq[0], b0, z, 0, 0, 0);
                z = __builtin_amdgcn_mfma_f32_16x16x32_bf16(aq[1], b1, z, 0, 0, 0);
                st[t] = z;
            }

#pragma unroll
            for (int t = 0; t < 2; ++t)
#pragma unroll
                for (int r = 0; r < 4; ++r) {
                    const int key  = sbase + cb + t * 16 + l15;
                    const int qrow = q0g + crow + r;
                    float p = __builtin_amdgcn_exp2f(st[t][r]);
                    p = (key <= qrow) ? p : 0.f;
                    lsum[r] += p;
                    Ps[w][crow + r][t * 16 + l15] = bf16bits(p);
                }

            asm volatile("s_waitcnt lgkmcnt(0)" ::: "memory");

            const short8 pa = *(const short8*)&Ps[w][l15][kq];
#pragma unroll
            for (int n = 0; n < 4; ++n) {
                const short8 bv = *(const short8*)&Vt[n * 16 + l15][cb + kq];
                O[n] = __builtin_amdgcn_mfma_f32_16x16x32_bf16(pa, bv, O[n], 0, 0, 0);
            }
        }
    }

#pragma unroll
    for (int off = 1; off < 16; off <<= 1)
#pragma unroll
        for (int r = 0; r < 4; ++r)
            lsum[r] += __shfl_xor(lsum[r], off, 16);

    float inv[4];
#pragma unroll
    for (int r = 0; r < 4; ++r) inv[r] = 1.f / lsum[r];
#pragma unroll
    for (int n = 0; n < 4; ++n)
#pragma unroll
        for (int r = 0; r < 4; ++r)
            out[(size_t)(b * 256 + q0g + crow + r) * 64 + n * 16 + l15] = O[n][r] * inv[r];
}

// ---------------------------------------------------------------------------
// Launch
// ---------------------------------------------------------------------------
extern "C" void kernel_launch(void* const* d_in, const int* in_sizes, int n_in,
                              void* d_out, int out_size, void* d_ws, size_t ws_size,
                              hipStream_t stream)
{
    const float* x  = (const float*)d_in[0];
    const float* Wq = (const float*)d_in[1];
    const float* Wk = (const float*)d_in[2];
    const float* Wv = (const float*)d_in[3];
    float* out = (float*)d_out;

    short* Wt = (short*)d_ws;
    short* qb = (short*)((char*)d_ws + 256 * 1024);
    short* kb = qb + (size_t)BT * HS;
    short* vT = kb + (size_t)BT * HS;

    prep_wt<<<(192 * 384) / 256, 256, 0, stream>>>(Wq, Wk, Wv, Wt);

    fused_head<<<BB, 512, 0, stream>>>(x, Wt, out);
    if (hipGetLastError() != hipSuccess) {
        // Fallback: proven R8 3-kernel path (same outputs).
        qkv_mfma<<<BT / 128, 256, 0, stream>>>(x, Wt, qb, kb, vT);
        attn_mfma<<<BB * 4, 256, 0, stream>>>(qb, kb, vT, out);
    }
}

// Round 10
// 172.060 us; speedup vs baseline: 1.1928x; 1.0564x over previous
//
#include <hip/hip_runtime.h>
#include <hip/hip_bf16.h>
#include <math.h>

// Problem constants
#define BB   256   // batch
#define TT   256   // sequence
#define CIN  384   // n_embed
#define HS   64    // head size
#define BT   (BB*TT)

// softmax scale folded into q at projection time: 384^-0.5 * log2(e)
#define QSCL ((float)(0.051031036307982884 * 1.4426950408889634))

typedef __attribute__((ext_vector_type(8))) short short8;   // 8 bf16 = 4 VGPR
typedef __attribute__((ext_vector_type(4))) float floatx4;  // MFMA C/D

__device__ inline short bf16bits(float f) {
    union { __hip_bfloat16 h; short s; } u;
    u.h = __float2bfloat16(f);
    return u.s;
}

__device__ inline short8 cvt8(const float4& f0, const float4& f1) {
    union { __hip_bfloat162 h[4]; short8 s8; } u;
    u.h[0] = __float22bfloat162_rn(make_float2(f0.x, f0.y));
    u.h[1] = __float22bfloat162_rn(make_float2(f0.z, f0.w));
    u.h[2] = __float22bfloat162_rn(make_float2(f1.x, f1.y));
    u.h[3] = __float22bfloat162_rn(make_float2(f1.z, f1.w));
    return u.s8;
}

// ---------------------------------------------------------------------------
// Kernel 0: pack Wq|Wk|Wv into WtP, a per-wave-instruction-contiguous bf16
// layout: for (wn,s,ks,nt) let X = ((wn*6+s)*2+ks)*6+nt; element (l15,quad,j)
// lives at X*512 + l15*32 + quad*8 + j. A B-frag wave load of
// WtP[X*512 + l15*32 + quad*8] is then ONE aligned 1 KB segment (previously
// 16 cache lines 768 B apart).
// ---------------------------------------------------------------------------
__global__ __launch_bounds__(256) void prep_wtp(
    const float* __restrict__ Wq, const float* __restrict__ Wk,
    const float* __restrict__ Wv, short* __restrict__ WtP)
{
    const int idx  = blockIdx.x * 256 + threadIdx.x;   // 0 .. 73727
    const int j    = idx & 7;
    const int quad = (idx >> 3) & 3;
    const int l15  = (idx >> 5) & 15;
    int X          = idx >> 9;          // 0..143
    const int nt   = X % 6;  X /= 6;
    const int ks   = X & 1;  X >>= 1;
    const int s    = X % 6;  X /= 6;
    const int wn   = X;                 // 0..1

    const int n  = wn * 96 + nt * 16 + l15;        // output column 0..191
    const int kk = s * 64 + ks * 32 + quad * 8 + j; // k index 0..383
    const float* W = (n < 64) ? Wq : (n < 128) ? Wk : Wv;
    WtP[idx] = bf16bits(W[kk * 64 + (n & 63)]);
}

// ---------------------------------------------------------------------------
// FUSED kernel: one block per batch element. 512 threads = 8 waves.
// Phase 1: QKV GEMM (M=256, N=192, K=384); wave (wm=w>>1, wn=w&1) owns
//   64M x 96N = 4x6 tiles. x staged in double-buffered [256][72] bf16 slabs;
//   *** 2-deep prefetch ***: while slab s computes, slab s+1 is already in
//   registers (loaded during s-1) and slab s+2's loads are issued.
//   B-frags from the coalesced WtP layout (one 1 KB segment per wave inst).
//   Outputs only to LDS: q (QSCL-prescaled), k, V transposed.
// Phase 2: causal attention entirely from LDS; unnormalized exp2 softmax;
//   P via wave-private LDS (m120 pattern); fp32 out stores.
// LDS (shorts): [0) stage/q [256][72]; [18432) stage/k [256][72];
//   [36864) vt [64][264]; [53760) Ps [8][16][40]; total 117760 B.
// ---------------------------------------------------------------------------
__global__ __launch_bounds__(512) void fused_head(
    const float* __restrict__ x, const short* __restrict__ WtP,
    float* __restrict__ out)
{
    __shared__ short smem[58880];   // 117760 B

    const int tid  = threadIdx.x;
    const int b    = blockIdx.x;
    const int lane = tid & 63;
    const int w    = tid >> 6;        // 0..7
    const int wm   = w >> 1;          // 0..3 : 64-row M strip
    const int wn   = w & 1;           // 0..1 : 96-col N half
    const int l15  = lane & 15;
    const int quad = lane >> 4;
    const int kq   = quad * 8;
    const int crow = quad * 4;

    const float* xb = x + (size_t)b * 256 * 384;
    const int laneoff = l15 * 32 + quad * 8;       // WtP per-lane offset

    floatx4 acc[4][6] = {};

    // ---- phase 1 prologue: stage slab 0 directly; preload slab 1 to regs --
#pragma unroll
    for (int i = 0; i < 4; ++i) {
        const int c   = i * 512 + tid;
        const int row = c >> 3;
        const int ch  = (c & 7) * 8;
        const float* p = xb + (size_t)row * 384 + ch;
        *(short8*)&smem[row * 72 + ch] = cvt8(*(const float4*)p, *(const float4*)(p + 4));
    }
    float4 pf[2][4][2];   // pf[slab&1] holds that slab's raw fp32
#pragma unroll
    for (int i = 0; i < 4; ++i) {
        const int c   = i * 512 + tid;
        const int row = c >> 3;
        const int ch  = (c & 7) * 8;
        const float* p = xb + (size_t)row * 384 + 64 + ch;   // slab 1
        pf[1][i][0] = *(const float4*)p;
        pf[1][i][1] = *(const float4*)(p + 4);
    }
    __syncthreads();

#pragma unroll
    for (int s = 0; s < 6; ++s) {
        short* cur = smem + (s & 1) * 18432;
        short* nxt = smem + ((s & 1) ^ 1) * 18432;

        // issue loads for slab s+2 (consumed NEXT iteration) -> pf[s&1]
        if (s < 4) {
#pragma unroll
            for (int i = 0; i < 4; ++i) {
                const int c   = i * 512 + tid;
                const int row = c >> 3;
                const int ch  = (c & 7) * 8;
                const float* p = xb + (size_t)row * 384 + (s + 2) * 64 + ch;
                pf[s & 1][i][0] = *(const float4*)p;
                pf[s & 1][i][1] = *(const float4*)(p + 4);
            }
        }

        // B fragments from coalesced WtP (1 KB/wave-inst, L2-hot)
        short8 bf[2][6];
#pragma unroll
        for (int ks = 0; ks < 2; ++ks)
#pragma unroll
            for (int nt = 0; nt < 6; ++nt)
                bf[ks][nt] = *(const short8*)
                    &WtP[((((wn * 6 + s) * 2 + ks) * 6 + nt) << 9) + laneoff];

        // compute slab s from LDS
#pragma unroll
        for (int ks = 0; ks < 2; ++ks) {
            short8 af[4];
#pragma unroll
            for (int mt = 0; mt < 4; ++mt)
                af[mt] = *(const short8*)&cur[(wm * 64 + mt * 16 + l15) * 72 + ks * 32 + kq];
#pragma unroll
            for (int mt = 0; mt < 4; ++mt)
#pragma unroll
                for (int nt = 0; nt < 6; ++nt)
                    acc[mt][nt] = __builtin_amdgcn_mfma_f32_16x16x32_bf16(
                        af[mt], bf[ks][nt], acc[mt][nt], 0, 0, 0);
        }

        // commit slab s+1 (register-resident since last iteration)
        if (s < 5) {
#pragma unroll
            for (int i = 0; i < 4; ++i) {
                const int c   = i * 512 + tid;
                const int row = c >> 3;
                const int ch  = (c & 7) * 8;
                *(short8*)&nxt[row * 72 + ch] =
                    cvt8(pf[(s + 1) & 1][i][0], pf[(s + 1) & 1][i][1]);
            }
        }
        __syncthreads();
    }

    // ---- phase 1 epilogue: q/k/vT into LDS (stage buffers are dead) ----
    short* q_lds = smem;             // [256][72]
    short* k_lds = smem + 18432;     // [256][72]
    short* vt    = smem + 36864;     // [64][264]
    short* Ps    = smem + 53760;     // [8][16][40]

    const int nbase = wn * 96;
#pragma unroll
    for (int nt = 0; nt < 6; ++nt) {
        const int n = nbase + nt * 16 + l15;
#pragma unroll
        for (int mt = 0; mt < 4; ++mt) {
#pragma unroll
            for (int r = 0; r < 4; ++r) {
                const int m = wm * 64 + mt * 16 + crow + r;   // token row 0..255
                const float av = acc[mt][nt][r];
                if (n < 64)       q_lds[m * 72 + n]          = bf16bits(av * QSCL);
                else if (n < 128) k_lds[m * 72 + (n - 64)]   = bf16bits(av);
                else              vt[(n - 128) * 264 + m]    = bf16bits(av);
            }
        }
    }
    __syncthreads();

    // ---- phase 2: attention from LDS. wave w owns rows w*32 .. w*32+31 ----
#pragma unroll
    for (int g = 0; g < 2; ++g) {
        const int r0 = w * 32 + g * 16;

        short8 aq0, aq1;
        aq0 = *(const short8*)&q_lds[(r0 + l15) * 72 + kq];
        aq1 = *(const short8*)&q_lds[(r0 + l15) * 72 + 32 + kq];

        float lsum[4] = {0.f, 0.f, 0.f, 0.f};
        floatx4 O[4] = {};

        const int nch = (r0 + 47) >> 5;   // chunks of 32 keys, causal bound
        for (int c = 0; c < nch; ++c) {
            const int cb = c * 32;

            floatx4 st[2];
#pragma unroll
            for (int t = 0; t < 2; ++t) {
                const short8 b0 = *(const short8*)&k_lds[(cb + t * 16 + l15) * 72 + kq];
                const short8 b1 = *(const short8*)&k_lds[(cb + t * 16 + l15) * 72 + 32 + kq];
                floatx4 z = {};
                z = __builtin_amdgcn_mfma_f32_16x16x32_bf16(aq0, b0, z, 0, 0, 0);
                z = __builtin_amdgcn_mfma_f32_16x16x32_bf16(aq1, b1, z, 0, 0, 0);
                st[t] = z;
            }

#pragma unroll
            for (int t = 0; t < 2; ++t)
#pragma unroll
                for (int r = 0; r < 4; ++r) {
                    const int key  = cb + t * 16 + l15;
                    const int qrow = r0 + crow + r;
                    float p = __builtin_amdgcn_exp2f(st[t][r]);
                    p = (key <= qrow) ? p : 0.f;
                    lsum[r] += p;
                    Ps[w * 640 + (crow + r) * 40 + t * 16 + l15] = bf16bits(p);
                }

            // wave-private LDS write->read ordering
            asm volatile("s_waitcnt lgkmcnt(0)" ::: "memory");

            const short8 pa = *(const short8*)&Ps[w * 640 + l15 * 40 + kq];
#pragma unroll
            for (int n = 0; n < 4; ++n) {
                const short8 bv = *(const short8*)&vt[(n * 16 + l15) * 264 + cb + kq];
                O[n] = __builtin_amdgcn_mfma_f32_16x16x32_bf16(pa, bv, O[n], 0, 0, 0);
            }
        }

#pragma unroll
        for (int off = 1; off < 16; off <<= 1)
#pragma unroll
            for (int r = 0; r < 4; ++r)
                lsum[r] += __shfl_xor(lsum[r], off, 16);

        float inv[4];
#pragma unroll
        for (int r = 0; r < 4; ++r) inv[r] = 1.f / lsum[r];
#pragma unroll
        for (int n = 0; n < 4; ++n)
#pragma unroll
            for (int r = 0; r < 4; ++r)
                out[(size_t)(b * 256 + r0 + crow + r) * 64 + n * 16 + l15] = O[n][r] * inv[r];
    }
}

// ---------------------------------------------------------------------------
// Launch
// ---------------------------------------------------------------------------
extern "C" void kernel_launch(void* const* d_in, const int* in_sizes, int n_in,
                              void* d_out, int out_size, void* d_ws, size_t ws_size,
                              hipStream_t stream)
{
    const float* x  = (const float*)d_in[0];
    const float* Wq = (const float*)d_in[1];
    const float* Wk = (const float*)d_in[2];
    const float* Wv = (const float*)d_in[3];
    float* out = (float*)d_out;

    short* WtP = (short*)d_ws;   // 73728 bf16 = 147456 B

    prep_wtp<<<(192 * 384) / 256, 256, 0, stream>>>(Wq, Wk, Wv, WtP);
    fused_head<<<BB, 512, 0, stream>>>(x, WtP, out);
}